// Round 1
// 579.778 us; speedup vs baseline: 1.0994x; 1.0994x over previous
//
#include <hip/hip_runtime.h>
#include <hip/hip_bf16.h>
#include <cstdint>

#define SEQ   8192
#define DIN   4096
#define DOUT  4096
#define RANK  16
#define NAD   8
#define KC    (DIN + NAD*RANK)   /* 4224 concatenated K */

using f32x4  = __attribute__((ext_vector_type(4))) float;
using bf16x8 = __attribute__((ext_vector_type(8))) short;   // 8 bf16 in 4 VGPRs

// fp32 -> bf16 round-to-nearest-even (inputs finite)
__device__ __forceinline__ unsigned short f2bf(float f) {
  union { float f; uint32_t u; } v; v.f = f;
  return (unsigned short)((v.u + 0x7fffu + ((v.u >> 16) & 1u)) >> 16);
}

// async global->LDS direct copy, 16B per lane (wave-uniform LDS base + lane*16)
__device__ __forceinline__ void async_copy16(void* lds, const void* gmem) {
  __builtin_amdgcn_global_load_lds(
      (__attribute__((address_space(1))) void*)(uintptr_t)gmem,
      (__attribute__((address_space(3))) void*)(uint32_t)(uintptr_t)lds,
      16, 0, 0);
}

// ---------------- conversion kernels ----------------

// x fp32 [SEQ][DIN] -> xcat bf16 rows of stride KC, cols 0..DIN-1
__global__ void cvt_x_kernel(const float* __restrict__ x, unsigned short* __restrict__ xcat) {
  const int64_t nchunks = (int64_t)SEQ * DIN / 8;
  for (int64_t c = (int64_t)blockIdx.x * blockDim.x + threadIdx.x; c < nchunks;
       c += (int64_t)gridDim.x * blockDim.x) {
    int64_t base = c * 8;
    int s = (int)(base >> 12);        // /DIN
    int k = (int)(base & (DIN - 1));
    float4 p = *(const float4*)(x + base);
    float4 q = *(const float4*)(x + base + 4);
    union { unsigned short h[8]; int4 v; } o;
    o.h[0]=f2bf(p.x); o.h[1]=f2bf(p.y); o.h[2]=f2bf(p.z); o.h[3]=f2bf(p.w);
    o.h[4]=f2bf(q.x); o.h[5]=f2bf(q.y); o.h[6]=f2bf(q.z); o.h[7]=f2bf(q.w);
    *(int4*)(xcat + (int64_t)s * KC + k) = o.v;
  }
}

// A_buffer fp32 [NAD*RANK][DIN] -> abf bf16 [128][DIN] (contiguous)
__global__ void cvt_a_kernel(const float* __restrict__ a, unsigned short* __restrict__ abf) {
  int c = blockIdx.x * 256 + threadIdx.x;     // 65536 chunks of 8
  int64_t base = (int64_t)c * 8;
  float4 p = *(const float4*)(a + base);
  float4 q = *(const float4*)(a + base + 4);
  union { unsigned short h[8]; int4 v; } o;
  o.h[0]=f2bf(p.x); o.h[1]=f2bf(p.y); o.h[2]=f2bf(p.z); o.h[3]=f2bf(p.w);
  o.h[4]=f2bf(q.x); o.h[5]=f2bf(q.y); o.h[6]=f2bf(q.z); o.h[7]=f2bf(q.w);
  *(int4*)(abf + base) = o.v;
}

// weight fp32 [DIN(k)][DOUT(n)] -> wcat bf16 [n][k] stride KC.
__global__ void cvt_w_kernel(const float* __restrict__ w, unsigned short* __restrict__ wcat) {
  int t  = threadIdx.x;
  int bn = blockIdx.x & 127;
  int bk = blockIdx.x >> 7;
  int n = bn * 32 + (t & 31);
  int k = bk * 64 + (t >> 5) * 8;
  union { unsigned short h[8]; int4 v; } o;
#pragma unroll
  for (int j = 0; j < 8; j++)
    o.h[j] = f2bf(w[(int64_t)(k + j) * DOUT + n]);
  *(int4*)(wcat + (int64_t)n * KC + k) = o.v;
}

// B_buffer fp32 [NAD][DOUT][RANK] -> wcat[n][DIN + e*16 + r]
__global__ void cvt_b_kernel(const float* __restrict__ Bbuf, unsigned short* __restrict__ wcat) {
  int idx = blockIdx.x * 256 + threadIdx.x;  // n*128 + er
  int n = idx >> 7, er = idx & 127;
  int e = er >> 4, r = er & 15;
  float v = Bbuf[((int64_t)e * DOUT + n) * RANK + r];
  wcat[(int64_t)n * KC + DIN + er] = f2bf(v);
}

// ---------------- LoRA-A projection GEMM (unchanged) ----------------
__global__ __launch_bounds__(256) void gemm_lora_a(
    const unsigned short* __restrict__ A,   // xcat
    const unsigned short* __restrict__ Bb,  // abf [128][DIN]
    float* __restrict__ aout) {             // [2][SEQ][128]
  constexpr int BK = 64;
  __shared__ unsigned short sA[64 * BK];    //  8 KB
  __shared__ unsigned short sB[128 * BK];   // 16 KB
  int tid = threadIdx.x, wave = tid >> 6, lane = tid & 63;
  int quad = lane >> 4, l16 = lane & 15;
  int mb = blockIdx.x & 127;                // 128 m-blocks
  int sp = blockIdx.x >> 7;                 // 2 K-splits
  int row0 = mb * 64;
  int kbase = sp * (DIN / 2);
  int wm = wave >> 1, wn = wave & 1;        // wave tile 32m x 64n
  int f8 = l16 & 7;                         // swizzle key (row&7 == l16&7)

  const f32x4 zero = {0.f, 0.f, 0.f, 0.f};
  f32x4 acc[2][4];
#pragma unroll
  for (int i = 0; i < 2; i++)
#pragma unroll
    for (int j = 0; j < 4; j++) acc[i][j] = zero;

  for (int kt = 0; kt < (DIN / 2) / BK; ++kt) {   // 32 iters
    int k0 = kbase + kt * BK;
#pragma unroll
    for (int i = 0; i < 2; i++) {            // A tile: 64x64 = 512 chunks
      int c = i * 256 + tid;
      int r = c >> 3, kc = ((c & 7) ^ (r & 7)) * 8;
      async_copy16(&sA[c * 8], A + (int64_t)(row0 + r) * KC + k0 + kc);
    }
#pragma unroll
    for (int i = 0; i < 4; i++) {            // B tile: 128x64 = 1024 chunks
      int c = i * 256 + tid;
      int r = c >> 3, kc = ((c & 7) ^ (r & 7)) * 8;
      async_copy16(&sB[c * 8], Bb + (int64_t)r * DIN + k0 + kc);
    }
    __syncthreads();
#pragma unroll
    for (int ks = 0; ks < 2; ks++) {
      bf16x8 af[2], bfr[4];
      int qq = ks * 4 + quad;
      int qp = (qq ^ f8) * 8;                // physical quarter (ushort offset)
#pragma unroll
      for (int mi = 0; mi < 2; mi++)
        af[mi] = *(const bf16x8*)&sA[(wm * 32 + mi * 16 + l16) * BK + qp];
#pragma unroll
      for (int ni = 0; ni < 4; ni++)
        bfr[ni] = *(const bf16x8*)&sB[(wn * 64 + ni * 16 + l16) * BK + qp];
#pragma unroll
      for (int mi = 0; mi < 2; mi++)
#pragma unroll
        for (int ni = 0; ni < 4; ni++)
          acc[mi][ni] = __builtin_amdgcn_mfma_f32_16x16x32_bf16(af[mi], bfr[ni], acc[mi][ni], 0, 0, 0);
    }
    __syncthreads();
  }

  float* op = aout + (int64_t)sp * SEQ * 128;
#pragma unroll
  for (int ni = 0; ni < 4; ni++) {
    int er = wn * 64 + ni * 16 + l16;
#pragma unroll
    for (int mi = 0; mi < 2; mi++) {
      int s0 = row0 + wm * 32 + mi * 16 + quad * 4;
#pragma unroll
      for (int r = 0; r < 4; r++)
        op[(int64_t)(s0 + r) * 128 + er] = acc[mi][ni][r];
    }
  }
}

// sum splits, scale, mask, write bf16 LoRA columns of xcat
__global__ void lora_combine(const float* __restrict__ aout, const float* __restrict__ scal,
                             const int* __restrict__ tok, unsigned short* __restrict__ xcat) {
  int idx = blockIdx.x * 256 + threadIdx.x;   // s*128 + er, 1M total
  int s = idx >> 7, er = idx & 127;
  float v = aout[idx] + aout[idx + (int64_t)SEQ * 128];
  v *= scal[s];
  v = ((er >> 4) == tok[s]) ? v : 0.0f;
  xcat[(int64_t)s * KC + DIN + er] = f2bf(v);
}

// ---------------- main GEMM: 256x256 tile, 8-phase counted-vmcnt schedule ----------------
// out[s][n] = sum_k xcat[s][k]*wcat[n][k] + bias[n], K=KC=4224 = 66 tiles of BK=64.
// 8 waves (2M x 4N), each owns a 128x64 output tile -> acc[8][4] f32x4.
// LDS: double-buffered A[256][64] + B[256][64] bf16 = 128 KiB (dynamic).
// Quarter swizzle: LDS slot (row, q) holds gmem 16B-quarter (q ^ (row&7));
// staged via pre-swizzled global source (linear LDS dest), read with same XOR
// -> ds_read_b128 fragment reads are 2-way max (free).
// Per tile, 4 phases = output quadrants (mq,nq)=(0,0),(0,1),(1,0),(1,1).
// Phase p reads A-half(mq), B-cols(nq); stages target regions whose last read
// ended at phase p-1 (freed by the end-of-phase barrier):
//   p0: stage A-mq1(tile+1)   p1: stage B-nq1(tile+1)
//   p2: stage A-mq0(tile+2)   p3: stage B-nq0(tile+2), then vmcnt(4)+barrier
// Boundary vmcnt(4): the 4 newer loads are tile+2's groups; everything tile+1
// needs is older -> landed. Never vmcnt(0) in the main loop.

#define CFENCE asm volatile("" ::: "memory")

template<int MQ, int NQ>
__device__ __forceinline__ void ds_loads(const unsigned short* aT, const unsigned short* bT,
                                         int wm, int wn, int l16, int quad,
                                         bf16x8 (&af)[4][2], bf16x8 (&bfr)[2][2]) {
  int f8 = l16 & 7;
#pragma unroll
  for (int ks = 0; ks < 2; ks++) {
    int qp = ((ks * 4 + quad) ^ f8) * 8;     // physical quarter, ushort offset
#pragma unroll
    for (int mi = 0; mi < 4; mi++)
      af[mi][ks] = *(const bf16x8*)&aT[(wm * 128 + MQ * 64 + mi * 16 + l16) * 64 + qp];
#pragma unroll
    for (int ni = 0; ni < 2; ni++)
      bfr[ni][ks] = *(const bf16x8*)&bT[(wn * 64 + NQ * 32 + ni * 16 + l16) * 64 + qp];
  }
}

template<int MQ, int NQ>
__device__ __forceinline__ void mfma_quad(f32x4 (&acc)[8][4], bf16x8 (&af)[4][2], bf16x8 (&bfr)[2][2]) {
  __builtin_amdgcn_s_setprio(1);
#pragma unroll
  for (int mi = 0; mi < 4; mi++)
#pragma unroll
    for (int ni = 0; ni < 2; ni++)
#pragma unroll
      for (int ks = 0; ks < 2; ks++)
        acc[MQ * 4 + mi][NQ * 2 + ni] = __builtin_amdgcn_mfma_f32_16x16x32_bf16(
            af[mi][ks], bfr[ni][ks], acc[MQ * 4 + mi][NQ * 2 + ni], 0, 0, 0);
  __builtin_amdgcn_s_setprio(0);
}

// stage A rows {mq*64..+64} u {128+mq*64..+64} of k-tile at col k0 (ushorts)
__device__ __forceinline__ void stage_A(unsigned short* sAb, const unsigned short* Ag,
                                        int mq, int k0, int tid) {
  int rr  = tid >> 3;
  int q8  = (tid & 7) * 8;
  int qc8 = ((tid & 7) ^ (rr & 7)) * 8;
  int r0 = mq * 64 + rr;
  async_copy16(sAb + r0 * 64 + q8, Ag + (int64_t)r0 * KC + k0 + qc8);
  int r1 = r0 + 128;
  async_copy16(sAb + r1 * 64 + q8, Ag + (int64_t)r1 * KC + k0 + qc8);
}

// stage B rows {nq*32 + 64j + 0..31 : j=0..3}
__device__ __forceinline__ void stage_B(unsigned short* sBb, const unsigned short* Bg,
                                        int nq, int k0, int tid) {
  int rB  = ((tid >> 3) & 31) | ((tid >> 8) << 6);
  int q8  = (tid & 7) * 8;
  int qc8 = ((tid & 7) ^ ((tid >> 3) & 7)) * 8;
  int r0 = nq * 32 + rB;
  async_copy16(sBb + r0 * 64 + q8, Bg + (int64_t)r0 * KC + k0 + qc8);
  int r1 = r0 + 128;
  async_copy16(sBb + r1 * 64 + q8, Bg + (int64_t)r1 * KC + k0 + qc8);
}

#define PHASE(MQ, NQ, aT, bT, STAGE_STMT)                        \
  ds_loads<MQ, NQ>(aT, bT, wm, wn, l16, quad, af, bfr);          \
  STAGE_STMT;                                                    \
  CFENCE; __builtin_amdgcn_s_barrier();                          \
  asm volatile("s_waitcnt lgkmcnt(0)" ::: "memory");             \
  mfma_quad<MQ, NQ>(acc, af, bfr)

#define ENDPHASE  CFENCE; __builtin_amdgcn_s_barrier(); CFENCE

__global__ __launch_bounds__(512, 2) void gemm_main8(
    const unsigned short* __restrict__ A,   // xcat [SEQ][KC]
    const unsigned short* __restrict__ B,   // wcat [DOUT][KC]
    const float* __restrict__ bias,
    float* __restrict__ out) {
  extern __shared__ unsigned short smem[];
  unsigned short* a0 = smem;                // A tile even (256x64)
  unsigned short* b0 = smem + 16384;        // B tile even
  unsigned short* a1 = smem + 32768;        // A tile odd
  unsigned short* b1 = smem + 49152;        // B tile odd

  int tid = threadIdx.x, wave = tid >> 6, lane = tid & 63;
  int quad = lane >> 4, l16 = lane & 15;
  int wm = wave >> 2, wn = wave & 3;        // 2M x 4N waves, 128x64 out each

  // XCD-bijective swizzle (512 blocks % 8 == 0)
  int bid = blockIdx.x;
  int cid = (bid & 7) * 64 + (bid >> 3);
  int bm = cid >> 4, bn = cid & 15;
  int row0 = bm * 256, col0 = bn * 256;

  const unsigned short* Ag = A + (int64_t)row0 * KC;
  const unsigned short* Bg = B + (int64_t)col0 * KC;

  const f32x4 zero = {0.f, 0.f, 0.f, 0.f};
  f32x4 acc[8][4];
#pragma unroll
  for (int i = 0; i < 8; i++)
#pragma unroll
    for (int j = 0; j < 4; j++) acc[i][j] = zero;

  bf16x8 af[4][2], bfr[2][2];

  // prologue: tile0 complete (8 loads) + tile1 A-mq0,B-nq0 (4 loads)
  stage_A(a0, Ag, 0, 0, tid);
  stage_B(b0, Bg, 0, 0, tid);
  stage_A(a0, Ag, 1, 0, tid);
  stage_B(b0, Bg, 1, 0, tid);
  stage_A(a1, Ag, 0, 64, tid);
  stage_B(b1, Bg, 0, 64, tid);
  asm volatile("s_waitcnt vmcnt(4)" ::: "memory");  // tile0's 8 oldest landed
  ENDPHASE;

  for (int tp = 0; tp < 32; ++tp) {         // steady tile pairs (0..63)
    int kE  = tp * 128;                     // even tile col base (ushorts)
    int kO  = kE + 64;                      // odd tile
    int kE2 = kE + 128;                     // tile+2 (even buffer)
    int kO2 = kE + 192;                     // tile+3 (odd buffer)
    // even tile (buf0)
    PHASE(0, 0, a0, b0, stage_A(a1, Ag, 1, kO,  tid)); ENDPHASE;
    PHASE(0, 1, a0, b0, stage_B(b1, Bg, 1, kO,  tid)); ENDPHASE;
    PHASE(1, 0, a0, b0, stage_A(a0, Ag, 0, kE2, tid)); ENDPHASE;
    PHASE(1, 1, a0, b0, stage_B(b0, Bg, 0, kE2, tid));
    asm volatile("s_waitcnt vmcnt(4)" ::: "memory");
    ENDPHASE;
    // odd tile (buf1)
    PHASE(0, 0, a1, b1, stage_A(a0, Ag, 1, kE2, tid)); ENDPHASE;
    PHASE(0, 1, a1, b1, stage_B(b0, Bg, 1, kE2, tid)); ENDPHASE;
    PHASE(1, 0, a1, b1, stage_A(a1, Ag, 0, kO2, tid)); ENDPHASE;
    PHASE(1, 1, a1, b1, stage_B(b1, Bg, 0, kO2, tid));
    asm volatile("s_waitcnt vmcnt(4)" ::: "memory");
    ENDPHASE;
  }

  // epilogue tiles 64 (buf0), 65 (buf1): k bases 4096, 4160
  PHASE(0, 0, a0, b0, stage_A(a1, Ag, 1, 4160, tid)); ENDPHASE;
  PHASE(0, 1, a0, b0, stage_B(b1, Bg, 1, 4160, tid)); ENDPHASE;
  PHASE(1, 0, a0, b0, ((void)0)); ENDPHASE;
  PHASE(1, 1, a0, b0, ((void)0));
  asm volatile("s_waitcnt vmcnt(0)" ::: "memory");    // drain: tile65 fully landed
  ENDPHASE;
  PHASE(0, 0, a1, b1, ((void)0)); ENDPHASE;
  PHASE(0, 1, a1, b1, ((void)0)); ENDPHASE;
  PHASE(1, 0, a1, b1, ((void)0)); ENDPHASE;
  PHASE(1, 1, a1, b1, ((void)0));

  // C write + bias
#pragma unroll
  for (int ni = 0; ni < 4; ni++) {
    int col = col0 + wn * 64 + ni * 16 + l16;
    float bv = bias[col];
#pragma unroll
    for (int mi = 0; mi < 8; mi++) {
      int rbase = row0 + wm * 128 + mi * 16 + quad * 4;
#pragma unroll
      for (int r = 0; r < 4; r++)
        out[(int64_t)(rbase + r) * DOUT + col] = acc[mi][ni][r] + bv;
    }
  }
}

// ---------------- slow fp32 fallback (ws too small insurance) ----------------
__global__ void fb_aout(const float* __restrict__ x, const float* __restrict__ Abuf,
                        const float* __restrict__ scal, const int* __restrict__ tok,
                        float* __restrict__ aout) {
  int s = blockIdx.x;
  int e = tok[s];
  __shared__ float red[256];
  for (int r = 0; r < RANK; ++r) {
    float p = 0.f;
    for (int k = threadIdx.x; k < DIN; k += 256)
      p += x[(int64_t)s * DIN + k] * Abuf[((int64_t)e * RANK + r) * DIN + k];
    red[threadIdx.x] = p;
    __syncthreads();
    for (int off = 128; off > 0; off >>= 1) {
      if (threadIdx.x < off) red[threadIdx.x] += red[threadIdx.x + off];
      __syncthreads();
    }
    if (threadIdx.x == 0) aout[s * RANK + r] = red[0] * scal[s];
    __syncthreads();
  }
}
__global__ void fb_out(const float* __restrict__ x, const float* __restrict__ w,
                       const float* __restrict__ bias, const float* __restrict__ Bbuf,
                       const int* __restrict__ tok, const float* __restrict__ aout,
                       float* __restrict__ out) {
  int64_t idx = (int64_t)blockIdx.x * blockDim.x + threadIdx.x;
  int s = (int)(idx >> 12), n = (int)(idx & (DOUT - 1));
  float accv = bias[n];
  for (int k = 0; k < DIN; ++k)
    accv += x[(int64_t)s * DIN + k] * w[(int64_t)k * DOUT + n];
  int e = tok[s];
  float d = 0.f;
  for (int r = 0; r < RANK; ++r)
    d += aout[s * RANK + r] * Bbuf[((int64_t)e * DOUT + n) * RANK + r];
  out[idx] = accv + d;
}

extern "C" void kernel_launch(void* const* d_in, const int* in_sizes, int n_in,
                              void* d_out, int out_size, void* d_ws, size_t ws_size,
                              hipStream_t stream) {
  const float* x    = (const float*)d_in[0];
  const float* w    = (const float*)d_in[1];
  const float* bias = (const float*)d_in[2];
  const float* Abuf = (const float*)d_in[3];
  const float* Bbuf = (const float*)d_in[4];
  const float* scal = (const float*)d_in[5];
  const int*   tok  = (const int*)d_in[6];
  float* out = (float*)d_out;

  const size_t xcat_b = (size_t)SEQ * KC * 2;          // 69,206,016 B
  const size_t wcat_b = (size_t)DOUT * KC * 2;         // 34,603,008 B
  const size_t abf_b  = (size_t)NAD * RANK * DIN * 2;  //  1,048,576 B
  const size_t aout_b = (size_t)2 * SEQ * 128 * 4;     //  8,388,608 B

  if (ws_size >= xcat_b + wcat_b + abf_b + aout_b) {
    static bool lds_attr_done = false;
    if (!lds_attr_done) {
      (void)hipFuncSetAttribute((const void*)gemm_main8,
                                hipFuncAttributeMaxDynamicSharedMemorySize, 131072);
      lds_attr_done = true;
    }
    unsigned short* xcat = (unsigned short*)d_ws;
    unsigned short* wcat = (unsigned short*)((char*)d_ws + xcat_b);
    unsigned short* abf  = (unsigned short*)((char*)d_ws + xcat_b + wcat_b);
    float*          aout = (float*)((char*)d_ws + xcat_b + wcat_b + abf_b);
    cvt_x_kernel<<<4096, 256, 0, stream>>>(x, xcat);
    cvt_w_kernel<<<8192, 256, 0, stream>>>(w, wcat);
    cvt_b_kernel<<<(DOUT * 128) / 256, 256, 0, stream>>>(Bbuf, wcat);
    cvt_a_kernel<<<(NAD * RANK * DIN / 8) / 256, 256, 0, stream>>>(Abuf, abf);
    gemm_lora_a<<<256, 256, 0, stream>>>(xcat, abf, aout);
    lora_combine<<<(SEQ * 128) / 256, 256, 0, stream>>>(aout, scal, tok, xcat);
    gemm_main8<<<512, 512, 131072, stream>>>(xcat, wcat, bias, out);
  } else {
    float* aout = (float*)d_ws;  // needs 512 KB
    fb_aout<<<SEQ, 256, 0, stream>>>(x, Abuf, scal, tok, aout);
    fb_out<<<(int)(((int64_t)SEQ * DOUT) / 256), 256, 0, stream>>>(x, w, bias, Bbuf, tok, aout, out);
  }
}

// Round 3
// 546.916 us; speedup vs baseline: 1.1654x; 1.0601x over previous
//
#include <hip/hip_runtime.h>
#include <hip/hip_bf16.h>
#include <cstdint>

#define SEQ   8192
#define DIN   4096
#define DOUT  4096
#define RANK  16
#define NAD   8
#define KC    (DIN + NAD*RANK)   /* 4224 concatenated K */

using f32x4  = __attribute__((ext_vector_type(4))) float;
using bf16x8 = __attribute__((ext_vector_type(8))) short;   // 8 bf16 in 4 VGPRs

// fp32 -> bf16 round-to-nearest-even (inputs finite)
__device__ __forceinline__ unsigned short f2bf(float f) {
  union { float f; uint32_t u; } v; v.f = f;
  return (unsigned short)((v.u + 0x7fffu + ((v.u >> 16) & 1u)) >> 16);
}

// async global->LDS direct copy, 16B per lane (wave-uniform LDS base + lane*16)
__device__ __forceinline__ void async_copy16(void* lds, const void* gmem) {
  __builtin_amdgcn_global_load_lds(
      (__attribute__((address_space(1))) void*)(uintptr_t)gmem,
      (__attribute__((address_space(3))) void*)(uint32_t)(uintptr_t)lds,
      16, 0, 0);
}

// ---------------- conversion kernels ----------------

// x fp32 [SEQ][DIN] -> xcat bf16 rows of stride KC, cols 0..DIN-1
__global__ void cvt_x_kernel(const float* __restrict__ x, unsigned short* __restrict__ xcat) {
  const int64_t nchunks = (int64_t)SEQ * DIN / 8;
  for (int64_t c = (int64_t)blockIdx.x * blockDim.x + threadIdx.x; c < nchunks;
       c += (int64_t)gridDim.x * blockDim.x) {
    int64_t base = c * 8;
    int s = (int)(base >> 12);        // /DIN
    int k = (int)(base & (DIN - 1));
    float4 p = *(const float4*)(x + base);
    float4 q = *(const float4*)(x + base + 4);
    union { unsigned short h[8]; int4 v; } o;
    o.h[0]=f2bf(p.x); o.h[1]=f2bf(p.y); o.h[2]=f2bf(p.z); o.h[3]=f2bf(p.w);
    o.h[4]=f2bf(q.x); o.h[5]=f2bf(q.y); o.h[6]=f2bf(q.z); o.h[7]=f2bf(q.w);
    *(int4*)(xcat + (int64_t)s * KC + k) = o.v;
  }
}

// A_buffer fp32 [NAD*RANK][DIN] -> abf bf16 [128][DIN] (contiguous)
__global__ void cvt_a_kernel(const float* __restrict__ a, unsigned short* __restrict__ abf) {
  int c = blockIdx.x * 256 + threadIdx.x;     // 65536 chunks of 8
  int64_t base = (int64_t)c * 8;
  float4 p = *(const float4*)(a + base);
  float4 q = *(const float4*)(a + base + 4);
  union { unsigned short h[8]; int4 v; } o;
  o.h[0]=f2bf(p.x); o.h[1]=f2bf(p.y); o.h[2]=f2bf(p.z); o.h[3]=f2bf(p.w);
  o.h[4]=f2bf(q.x); o.h[5]=f2bf(q.y); o.h[6]=f2bf(q.z); o.h[7]=f2bf(q.w);
  *(int4*)(abf + base) = o.v;
}

// weight fp32 [DIN(k)][DOUT(n)] -> wcat bf16 [n][k] stride KC.
__global__ void cvt_w_kernel(const float* __restrict__ w, unsigned short* __restrict__ wcat) {
  int t  = threadIdx.x;
  int bn = blockIdx.x & 127;
  int bk = blockIdx.x >> 7;
  int n = bn * 32 + (t & 31);
  int k = bk * 64 + (t >> 5) * 8;
  union { unsigned short h[8]; int4 v; } o;
#pragma unroll
  for (int j = 0; j < 8; j++)
    o.h[j] = f2bf(w[(int64_t)(k + j) * DOUT + n]);
  *(int4*)(wcat + (int64_t)n * KC + k) = o.v;
}

// B_buffer fp32 [NAD][DOUT][RANK] -> wcat[n][DIN + e*16 + r]
__global__ void cvt_b_kernel(const float* __restrict__ Bbuf, unsigned short* __restrict__ wcat) {
  int idx = blockIdx.x * 256 + threadIdx.x;  // n*128 + er
  int n = idx >> 7, er = idx & 127;
  int e = er >> 4, r = er & 15;
  float v = Bbuf[((int64_t)e * DOUT + n) * RANK + r];
  wcat[(int64_t)n * KC + DIN + er] = f2bf(v);
}

// ---------------- LoRA-A projection GEMM (unchanged) ----------------
__global__ __launch_bounds__(256) void gemm_lora_a(
    const unsigned short* __restrict__ A,   // xcat
    const unsigned short* __restrict__ Bb,  // abf [128][DIN]
    float* __restrict__ aout) {             // [2][SEQ][128]
  constexpr int BK = 64;
  __shared__ unsigned short sA[64 * BK];    //  8 KB
  __shared__ unsigned short sB[128 * BK];   // 16 KB
  int tid = threadIdx.x, wave = tid >> 6, lane = tid & 63;
  int quad = lane >> 4, l16 = lane & 15;
  int mb = blockIdx.x & 127;                // 128 m-blocks
  int sp = blockIdx.x >> 7;                 // 2 K-splits
  int row0 = mb * 64;
  int kbase = sp * (DIN / 2);
  int wm = wave >> 1, wn = wave & 1;        // wave tile 32m x 64n
  int f8 = l16 & 7;                         // swizzle key (row&7 == l16&7)

  const f32x4 zero = {0.f, 0.f, 0.f, 0.f};
  f32x4 acc[2][4];
#pragma unroll
  for (int i = 0; i < 2; i++)
#pragma unroll
    for (int j = 0; j < 4; j++) acc[i][j] = zero;

  for (int kt = 0; kt < (DIN / 2) / BK; ++kt) {   // 32 iters
    int k0 = kbase + kt * BK;
#pragma unroll
    for (int i = 0; i < 2; i++) {            // A tile: 64x64 = 512 chunks
      int c = i * 256 + tid;
      int r = c >> 3, kc = ((c & 7) ^ (r & 7)) * 8;
      async_copy16(&sA[c * 8], A + (int64_t)(row0 + r) * KC + k0 + kc);
    }
#pragma unroll
    for (int i = 0; i < 4; i++) {            // B tile: 128x64 = 1024 chunks
      int c = i * 256 + tid;
      int r = c >> 3, kc = ((c & 7) ^ (r & 7)) * 8;
      async_copy16(&sB[c * 8], Bb + (int64_t)r * DIN + k0 + kc);
    }
    __syncthreads();
#pragma unroll
    for (int ks = 0; ks < 2; ks++) {
      bf16x8 af[2], bfr[4];
      int qq = ks * 4 + quad;
      int qp = (qq ^ f8) * 8;                // physical quarter (ushort offset)
#pragma unroll
      for (int mi = 0; mi < 2; mi++)
        af[mi] = *(const bf16x8*)&sA[(wm * 32 + mi * 16 + l16) * BK + qp];
#pragma unroll
      for (int ni = 0; ni < 4; ni++)
        bfr[ni] = *(const bf16x8*)&sB[(wn * 64 + ni * 16 + l16) * BK + qp];
#pragma unroll
      for (int mi = 0; mi < 2; mi++)
#pragma unroll
        for (int ni = 0; ni < 4; ni++)
          acc[mi][ni] = __builtin_amdgcn_mfma_f32_16x16x32_bf16(af[mi], bfr[ni], acc[mi][ni], 0, 0, 0);
    }
    __syncthreads();
  }

  float* op = aout + (int64_t)sp * SEQ * 128;
#pragma unroll
  for (int ni = 0; ni < 4; ni++) {
    int er = wn * 64 + ni * 16 + l16;
#pragma unroll
    for (int mi = 0; mi < 2; mi++) {
      int s0 = row0 + wm * 32 + mi * 16 + quad * 4;
#pragma unroll
      for (int r = 0; r < 4; r++)
        op[(int64_t)(s0 + r) * 128 + er] = acc[mi][ni][r];
    }
  }
}

// sum splits, scale, mask, write bf16 LoRA columns of xcat
__global__ void lora_combine(const float* __restrict__ aout, const float* __restrict__ scal,
                             const int* __restrict__ tok, unsigned short* __restrict__ xcat) {
  int idx = blockIdx.x * 256 + threadIdx.x;   // s*128 + er, 1M total
  int s = idx >> 7, er = idx & 127;
  float v = aout[idx] + aout[idx + (int64_t)SEQ * 128];
  v *= scal[s];
  v = ((er >> 4) == tok[s]) ? v : 0.0f;
  xcat[(int64_t)s * KC + DIN + er] = f2bf(v);
}

// ---------------- main GEMM: 256x256 tile, zig-zag 8-phase, vmcnt(6) ----------------
// out[s][n] = sum_k xcat[s][k]*wcat[n][k] + bias[n], K=KC=4224 = 66 tiles of BK=64.
// 8 waves (2M x 4N), each owns a 128x64 output tile -> acc[8][4] f32x4.
// LDS: double-buffered A[256][64] + B[256][64] bf16 = 128 KiB (dynamic).
// Quarter swizzle (both-sides): LDS slot (row,q) holds gmem quarter q^(row&7).
// Zig-zag quadrant order (0,0)->(0,1)->(1,1)->(1,0) with operand reuse in regs:
// LDS reads/tile/wave = 24 b128 (A0:8, B1:4, A1:8; B0 held in regs p0->p3).
// Stage schedule: each phase stages the region freed by the previous phase:
//   p0: other-buf B0 <- t+1;  p1: A0 <- t+2;  p2: B1 <- t+2;  p3: A1 <- t+2
// Boundary s_waitcnt vmcnt(6): the 6 newest loads are t+2's (p1..p3 groups);
// everything tile t+1 reads is older -> landed. Never vmcnt(0) in main loop.

#define CFENCE asm volatile("" ::: "memory")

template<int MQ>
__device__ __forceinline__ void ldsA(const unsigned short* aT, int wm, int l16, int quad,
                                     bf16x8 (&af)[4][2]) {
  int f8 = l16 & 7;
#pragma unroll
  for (int ks = 0; ks < 2; ks++) {
    int qp = ((ks * 4 + quad) ^ f8) * 8;     // physical quarter, ushort offset
#pragma unroll
    for (int mi = 0; mi < 4; mi++)
      af[mi][ks] = *(const bf16x8*)&aT[(wm * 128 + MQ * 64 + mi * 16 + l16) * 64 + qp];
  }
}

template<int NQ>
__device__ __forceinline__ void ldsB(const unsigned short* bT, int wn, int l16, int quad,
                                     bf16x8 (&bq)[2][2]) {
  int f8 = l16 & 7;
#pragma unroll
  for (int ks = 0; ks < 2; ks++) {
    int qp = ((ks * 4 + quad) ^ f8) * 8;
#pragma unroll
    for (int ni = 0; ni < 2; ni++)
      bq[ni][ks] = *(const bf16x8*)&bT[(wn * 64 + NQ * 32 + ni * 16 + l16) * 64 + qp];
  }
}

template<int MQ, int NQ>
__device__ __forceinline__ void mfma_quad(f32x4 (&acc)[8][4], bf16x8 (&af)[4][2],
                                          bf16x8 (&bq)[2][2]) {
  __builtin_amdgcn_s_setprio(1);
#pragma unroll
  for (int mi = 0; mi < 4; mi++)
#pragma unroll
    for (int ni = 0; ni < 2; ni++)
#pragma unroll
      for (int ks = 0; ks < 2; ks++)
        acc[MQ * 4 + mi][NQ * 2 + ni] = __builtin_amdgcn_mfma_f32_16x16x32_bf16(
            af[mi][ks], bq[ni][ks], acc[MQ * 4 + mi][NQ * 2 + ni], 0, 0, 0);
  __builtin_amdgcn_s_setprio(0);
}

// stage A rows {mq*64..+64} u {128+mq*64..+64} of k-tile at col k0 (ushorts)
__device__ __forceinline__ void stage_A(unsigned short* sAb, const unsigned short* Ag,
                                        int mq, int k0, int tid) {
  int rr  = tid >> 3;
  int q8  = (tid & 7) * 8;
  int qc8 = ((tid & 7) ^ (rr & 7)) * 8;
  int r0 = mq * 64 + rr;
  async_copy16(sAb + r0 * 64 + q8, Ag + (int64_t)r0 * KC + k0 + qc8);
  int r1 = r0 + 128;
  async_copy16(sAb + r1 * 64 + q8, Ag + (int64_t)r1 * KC + k0 + qc8);
}

// stage B rows {nq*32 + 64j + 0..31 : j=0..3}
__device__ __forceinline__ void stage_B(unsigned short* sBb, const unsigned short* Bg,
                                        int nq, int k0, int tid) {
  int rB  = ((tid >> 3) & 31) | ((tid >> 8) << 6);
  int q8  = (tid & 7) * 8;
  int qc8 = ((tid & 7) ^ ((tid >> 3) & 7)) * 8;
  int r0 = nq * 32 + rB;
  async_copy16(sBb + r0 * 64 + q8, Bg + (int64_t)r0 * KC + k0 + qc8);
  int r1 = r0 + 128;
  async_copy16(sBb + r1 * 64 + q8, Bg + (int64_t)r1 * KC + k0 + qc8);
}

#define MIDBAR                                                    \
  CFENCE; __builtin_amdgcn_s_barrier();                           \
  asm volatile("s_waitcnt lgkmcnt(0)" ::: "memory")
#define ENDBAR  CFENCE; __builtin_amdgcn_s_barrier(); CFENCE

// One K-tile: 4 zig-zag phases, 7 barriers, stages S0..S3, boundary wait BND.
#define TILE(aT, bT, S0, S1, S2, S3, BND)                         \
  ldsA<0>(aT, wm, l16, quad, af);                                 \
  ldsB<0>(bT, wn, l16, quad, bf0);                                \
  S0; MIDBAR;                                                     \
  mfma_quad<0, 0>(acc, af, bf0);                                  \
  ENDBAR;                                                         \
  ldsB<1>(bT, wn, l16, quad, bf1);                                \
  S1; MIDBAR;                                                     \
  mfma_quad<0, 1>(acc, af, bf1);                                  \
  ENDBAR;                                                         \
  ldsA<1>(aT, wm, l16, quad, af);                                 \
  S2; MIDBAR;                                                     \
  mfma_quad<1, 1>(acc, af, bf1);                                  \
  ENDBAR;                                                         \
  S3; CFENCE;                                                     \
  mfma_quad<1, 0>(acc, af, bf0);                                  \
  BND;                                                            \
  ENDBAR

__global__ __launch_bounds__(512, 2) void gemm_main8(
    const unsigned short* __restrict__ A,   // xcat [SEQ][KC]
    const unsigned short* __restrict__ B,   // wcat [DOUT][KC]
    const float* __restrict__ bias,
    float* __restrict__ out) {
  extern __shared__ unsigned short smem[];
  unsigned short* a0 = smem;                // A tile even (256x64)
  unsigned short* b0 = smem + 16384;        // B tile even
  unsigned short* a1 = smem + 32768;        // A tile odd
  unsigned short* b1 = smem + 49152;        // B tile odd

  int tid = threadIdx.x, wave = tid >> 6, lane = tid & 63;
  int quad = lane >> 4, l16 = lane & 15;
  int wm = wave >> 2, wn = wave & 3;        // 2M x 4N waves, 128x64 out each

  // XCD-bijective swizzle (512 blocks % 8 == 0)
  int bid = blockIdx.x;
  int cid = (bid & 7) * 64 + (bid >> 3);
  int bm = cid >> 4, bn = cid & 15;
  int row0 = bm * 256, col0 = bn * 256;

  const unsigned short* Ag = A + (int64_t)row0 * KC;
  const unsigned short* Bg = B + (int64_t)col0 * KC;

  const f32x4 zero = {0.f, 0.f, 0.f, 0.f};
  f32x4 acc[8][4];
#pragma unroll
  for (int i = 0; i < 8; i++)
#pragma unroll
    for (int j = 0; j < 4; j++) acc[i][j] = zero;

  bf16x8 af[4][2], bf0[2][2], bf1[2][2];

  // prologue: tile0 complete (A0,B0,B1,A1) + tile1 {A0,B1,A1} -> 14 loads
  stage_A(a0, Ag, 0, 0, tid);
  stage_B(b0, Bg, 0, 0, tid);
  stage_B(b0, Bg, 1, 0, tid);
  stage_A(a0, Ag, 1, 0, tid);
  stage_A(a1, Ag, 0, 64, tid);
  stage_B(b1, Bg, 1, 64, tid);
  stage_A(a1, Ag, 1, 64, tid);
  asm volatile("s_waitcnt vmcnt(6)" ::: "memory");  // tile0's 8 landed
  ENDBAR;

#define BND6 asm volatile("s_waitcnt vmcnt(6)" ::: "memory")

  for (int tp = 0; tp < 32; ++tp) {         // tiles 0..63, steady zig-zag
    int kE = tp * 128;
    // even tile 2tp (buf0): t+1 = buf1 @ kE+64, t+2 = buf0 @ kE+128
    TILE(a0, b0,
         stage_B(b1, Bg, 0, kE + 64,  tid),
         stage_A(a0, Ag, 0, kE + 128, tid),
         stage_B(b0, Bg, 1, kE + 128, tid),
         stage_A(a0, Ag, 1, kE + 128, tid),
         BND6);
    // odd tile 2tp+1 (buf1): t+1 = buf0 @ kE+128, t+2 = buf1 @ kE+192
    TILE(a1, b1,
         stage_B(b0, Bg, 0, kE + 128, tid),
         stage_A(a1, Ag, 0, kE + 192, tid),
         stage_B(b1, Bg, 1, kE + 192, tid),
         stage_A(a1, Ag, 1, kE + 192, tid),
         BND6);
  }

  // tile 64 (buf0): only t65's B0 remains to stage; drain fully at boundary
  TILE(a0, b0,
       stage_B(b1, Bg, 0, 4160, tid),
       (void)0, (void)0, (void)0,
       asm volatile("s_waitcnt vmcnt(0)" ::: "memory"));

  // tile 65 (buf1): everything resident, no stages -> no barriers needed
  ldsA<0>(a1, wm, l16, quad, af);
  ldsB<0>(b1, wn, l16, quad, bf0);
  mfma_quad<0, 0>(acc, af, bf0);
  ldsB<1>(b1, wn, l16, quad, bf1);
  mfma_quad<0, 1>(acc, af, bf1);
  ldsA<1>(a1, wm, l16, quad, af);
  mfma_quad<1, 1>(acc, af, bf1);
  mfma_quad<1, 0>(acc, af, bf0);

  // C write + bias
#pragma unroll
  for (int ni = 0; ni < 4; ni++) {
    int col = col0 + wn * 64 + ni * 16 + l16;
    float bv = bias[col];
#pragma unroll
    for (int mi = 0; mi < 8; mi++) {
      int rbase = row0 + wm * 128 + mi * 16 + quad * 4;
#pragma unroll
      for (int r = 0; r < 4; r++)
        out[(int64_t)(rbase + r) * DOUT + col] = acc[mi][ni][r] + bv;
    }
  }
}

// ---------------- slow fp32 fallback (ws too small insurance) ----------------
__global__ void fb_aout(const float* __restrict__ x, const float* __restrict__ Abuf,
                        const float* __restrict__ scal, const int* __restrict__ tok,
                        float* __restrict__ aout) {
  int s = blockIdx.x;
  int e = tok[s];
  __shared__ float red[256];
  for (int r = 0; r < RANK; ++r) {
    float p = 0.f;
    for (int k = threadIdx.x; k < DIN; k += 256)
      p += x[(int64_t)s * DIN + k] * Abuf[((int64_t)e * RANK + r) * DIN + k];
    red[threadIdx.x] = p;
    __syncthreads();
    for (int off = 128; off > 0; off >>= 1) {
      if (threadIdx.x < off) red[threadIdx.x] += red[threadIdx.x + off];
      __syncthreads();
    }
    if (threadIdx.x == 0) aout[s * RANK + r] = red[0] * scal[s];
    __syncthreads();
  }
}
__global__ void fb_out(const float* __restrict__ x, const float* __restrict__ w,
                       const float* __restrict__ bias, const float* __restrict__ Bbuf,
                       const int* __restrict__ tok, const float* __restrict__ aout,
                       float* __restrict__ out) {
  int64_t idx = (int64_t)blockIdx.x * blockDim.x + threadIdx.x;
  int s = (int)(idx >> 12), n = (int)(idx & (DOUT - 1));
  float accv = bias[n];
  for (int k = 0; k < DIN; ++k)
    accv += x[(int64_t)s * DIN + k] * w[(int64_t)k * DOUT + n];
  int e = tok[s];
  float d = 0.f;
  for (int r = 0; r < RANK; ++r)
    d += aout[s * RANK + r] * Bbuf[((int64_t)e * DOUT + n) * RANK + r];
  out[idx] = accv + d;
}

extern "C" void kernel_launch(void* const* d_in, const int* in_sizes, int n_in,
                              void* d_out, int out_size, void* d_ws, size_t ws_size,
                              hipStream_t stream) {
  const float* x    = (const float*)d_in[0];
  const float* w    = (const float*)d_in[1];
  const float* bias = (const float*)d_in[2];
  const float* Abuf = (const float*)d_in[3];
  const float* Bbuf = (const float*)d_in[4];
  const float* scal = (const float*)d_in[5];
  const int*   tok  = (const int*)d_in[6];
  float* out = (float*)d_out;

  const size_t xcat_b = (size_t)SEQ * KC * 2;          // 69,206,016 B
  const size_t wcat_b = (size_t)DOUT * KC * 2;         // 34,603,008 B
  const size_t abf_b  = (size_t)NAD * RANK * DIN * 2;  //  1,048,576 B
  const size_t aout_b = (size_t)2 * SEQ * 128 * 4;     //  8,388,608 B

  if (ws_size >= xcat_b + wcat_b + abf_b + aout_b) {
    static bool lds_attr_done = false;
    if (!lds_attr_done) {
      (void)hipFuncSetAttribute((const void*)gemm_main8,
                                hipFuncAttributeMaxDynamicSharedMemorySize, 131072);
      lds_attr_done = true;
    }
    unsigned short* xcat = (unsigned short*)d_ws;
    unsigned short* wcat = (unsigned short*)((char*)d_ws + xcat_b);
    unsigned short* abf  = (unsigned short*)((char*)d_ws + xcat_b + wcat_b);
    float*          aout = (float*)((char*)d_ws + xcat_b + wcat_b + abf_b);
    cvt_x_kernel<<<4096, 256, 0, stream>>>(x, xcat);
    cvt_w_kernel<<<8192, 256, 0, stream>>>(w, wcat);
    cvt_b_kernel<<<(DOUT * 128) / 256, 256, 0, stream>>>(Bbuf, wcat);
    cvt_a_kernel<<<(NAD * RANK * DIN / 8) / 256, 256, 0, stream>>>(Abuf, abf);
    gemm_lora_a<<<256, 256, 0, stream>>>(xcat, abf, aout);
    lora_combine<<<(SEQ * 128) / 256, 256, 0, stream>>>(aout, scal, tok, xcat);
    gemm_main8<<<512, 512, 131072, stream>>>(xcat, wcat, bias, out);
  } else {
    float* aout = (float*)d_ws;  // needs 512 KB
    fb_aout<<<SEQ, 256, 0, stream>>>(x, Abuf, scal, tok, aout);
    fb_out<<<(int)(((int64_t)SEQ * DOUT) / 256), 256, 0, stream>>>(x, w, bias, Bbuf, tok, aout, out);
  }
}